// Round 5
// baseline (633.090 us; speedup 1.0000x reference)
//
#include <hip/hip_runtime.h>

#define HID 64
#define SCAN_B 128
#define SCAN_T 256
#define NXCD 8

// ---------------- CSR build (XCD-partitioned by dst range) ----------------

__global__ __launch_bounds__(256) void count_part(const int* __restrict__ ei, int E, int N,
                                                  int* __restrict__ cnt) {
    int xcd = blockIdx.x & (NXCD - 1);
    int sl = blockIdx.x >> 3;
    int nsl = gridDim.x >> 3;
    int nlo = (int)((long long)N * xcd / NXCD);
    int nhi = (int)((long long)N * (xcd + 1) / NXCD);
    int stride = nsl * blockDim.x;
    for (int e = sl * blockDim.x + threadIdx.x; e < E; e += stride) {
        int d = ei[E + e];
        if (d >= nlo && d < nhi) atomicAdd(&cnt[d], 1);
    }
}

__global__ __launch_bounds__(256) void fill_part(const int* __restrict__ ei, int E, int N,
                                                 const float* __restrict__ dinv,
                                                 int* __restrict__ cursor,
                                                 int2* __restrict__ csr) {
    int xcd = blockIdx.x & (NXCD - 1);
    int sl = blockIdx.x >> 3;
    int nsl = gridDim.x >> 3;
    int nlo = (int)((long long)N * xcd / NXCD);
    int nhi = (int)((long long)N * (xcd + 1) / NXCD);
    int stride = nsl * blockDim.x;
    for (int e = sl * blockDim.x + threadIdx.x; e < E; e += stride) {
        int d = ei[E + e];
        if (d >= nlo && d < nhi) {
            int s = ei[e];
            int pos = atomicAdd(&cursor[d], 1);
            csr[pos] = make_int2(s, __float_as_int(dinv[s]));
        }
    }
}

__global__ void dinv_kernel(const int* __restrict__ cnt, float* __restrict__ dinv, int N) {
    int stride = gridDim.x * blockDim.x;
    for (int n = blockIdx.x * blockDim.x + threadIdx.x; n < N; n += stride)
        dinv[n] = rsqrtf((float)(cnt[n] + 1));  // deg includes self-loop
}

// graph boundaries from sorted batch: gb[g] = first node with batch >= g; gb[G] = N
__global__ void bounds_kernel(const int* __restrict__ batch, int* __restrict__ gb, int N, int G) {
    int n = blockIdx.x * blockDim.x + threadIdx.x;
    if (n >= N) return;
    int b = batch[n];
    if (n == 0) {
        for (int g = 0; g <= b; g++) gb[g] = 0;
    } else {
        int pb = batch[n - 1];
        for (int g = pb + 1; g <= b; g++) gb[g] = n;
    }
    if (n == N - 1) {
        for (int g = b + 1; g <= G; g++) gb[g] = N;
    }
}

__global__ void scan_sum(const int* __restrict__ cnt, int N, int* __restrict__ bsum) {
    int b = blockIdx.x;
    int chunk = (N + SCAN_B - 1) / SCAN_B;
    int lo = b * chunk, hi = min(lo + chunk, N);
    int s = 0;
    for (int i = lo + threadIdx.x; i < hi; i += SCAN_T) s += cnt[i];
    for (int off = 32; off; off >>= 1) s += __shfl_xor(s, off);
    __shared__ int red[SCAN_T / 64];
    int wave = threadIdx.x >> 6, lane = threadIdx.x & 63;
    if (lane == 0) red[wave] = s;
    __syncthreads();
    if (threadIdx.x == 0) {
        int t = 0;
        for (int w = 0; w < SCAN_T / 64; w++) t += red[w];
        bsum[b] = t;
    }
}

__global__ void scan_bsum(const int* __restrict__ bsum, int* __restrict__ bofs) {
    if (blockIdx.x == 0 && threadIdx.x == 0) {
        int r = 0;
        for (int b = 0; b < SCAN_B; b++) { bofs[b] = r; r += bsum[b]; }
    }
}

__global__ void scan_chunk(const int* __restrict__ cnt, int N, const int* __restrict__ bofs,
                           int* __restrict__ row_start, int* __restrict__ cursor) {
    int b = blockIdx.x;
    int chunk = (N + SCAN_B - 1) / SCAN_B;
    int lo = b * chunk, hi = min(lo + chunk, N);
    __shared__ int s[SCAN_T];
    __shared__ int carry;
    if (threadIdx.x == 0) carry = bofs[b];
    __syncthreads();
    for (int base = lo; base < hi; base += SCAN_T) {
        int i = base + threadIdx.x;
        int v = (i < hi) ? cnt[i] : 0;
        s[threadIdx.x] = v;
        __syncthreads();
        for (int off = 1; off < SCAN_T; off <<= 1) {
            int t = (threadIdx.x >= off) ? s[threadIdx.x - off] : 0;
            __syncthreads();
            s[threadIdx.x] += t;
            __syncthreads();
        }
        int incl = s[threadIdx.x];
        int c = carry;
        if (i < hi) {
            int ex = c + incl - v;
            row_start[i] = ex;
            cursor[i] = ex;
        }
        __syncthreads();
        if (threadIdx.x == SCAN_T - 1) carry = c + incl;
        __syncthreads();
    }
}

// ---------------- Layer 1: scalar propagate + fused (relu(p*W1+b1)) @ W2, sliced write ----
// wave per node; quarter-split matmul; output in sliced layout [8][N][8]

__global__ __launch_bounds__(256) void layer1_kernel(
    const float* __restrict__ x, const int2* __restrict__ csr,
    const int* __restrict__ row_start, const int* __restrict__ cnt, const float* __restrict__ dinv,
    const float* __restrict__ W1, const float* __restrict__ b1, const float* __restrict__ W2,
    float* __restrict__ zs, int N) {
    int lane = threadIdx.x & 63;
    int q = lane >> 4, sl = lane & 15;
    // W2 slice in registers: rows q*16..q*16+15, cols [4sl..4sl+3]
    float4 wreg[16];
#pragma unroll
    for (int t = 0; t < 16; t++)
        wreg[t] = *reinterpret_cast<const float4*>(&W2[((q << 4) + t) * HID + (sl << 2)]);
    int n = blockIdx.x * 4 + (threadIdx.x >> 6);
    if (n >= N) return;
    int start = row_start[n], deg = cnt[n];
    float acc = 0.f;
    for (int i = start + lane; i < start + deg; i += 64) {
        int2 ew = csr[i];
        acc += __int_as_float(ew.y) * x[ew.x];
    }
#pragma unroll
    for (int off = 32; off; off >>= 1) acc += __shfl_xor(acc, off);
    float dn = dinv[n];
    float p = dn * (acc + dn * x[n]);  // wave-uniform
    // h[lane] = relu(p*W1[lane]+b1[lane]); one feature per lane
    float h = fmaxf(p * W1[lane] + b1[lane], 0.f);
    float4 zv = make_float4(0.f, 0.f, 0.f, 0.f);
#pragma unroll
    for (int t = 0; t < 16; t++) {
        float hk = __shfl(h, (q << 4) + t);
        zv.x += hk * wreg[t].x; zv.y += hk * wreg[t].y;
        zv.z += hk * wreg[t].z; zv.w += hk * wreg[t].w;
    }
#pragma unroll
    for (int off = 16; off <= 32; off <<= 1) {
        zv.x += __shfl_xor(zv.x, off);
        zv.y += __shfl_xor(zv.y, off);
        zv.z += __shfl_xor(zv.z, off);
        zv.w += __shfl_xor(zv.w, off);
    }
    if (q == 0)  // features [4sl..4sl+3] -> slice sl>>1, offset (sl&1)*4
        *reinterpret_cast<float4*>(
            &zs[(size_t)(sl >> 1) * N * 8 + (size_t)n * 8 + ((sl & 1) << 2)]) = zv;
}

// ---------------- sliced propagate: y = P(z), both [8][N][8] ----------------
// block -> XCD via blockIdx&7 owns feature slice s (3.2 MB, L2-resident).
// wave: 8 groups x 8 feature-lanes; 4 interleaved node-chains for MLP.

__global__ __launch_bounds__(256) void psli_kernel(
    const float* __restrict__ zs, const int2* __restrict__ csr,
    const int* __restrict__ row_start, const int* __restrict__ cnt,
    const float* __restrict__ dinv, float* __restrict__ ys, int N, int E) {
    int s = blockIdx.x & (NXCD - 1);
    int wid = threadIdx.x >> 6, lane = threadIdx.x & 63;
    int grp = lane >> 3, f = lane & 7;
    const float* __restrict__ z = zs + (size_t)s * N * 8;
    float* __restrict__ y = ys + (size_t)s * N * 8;
    int n0 = ((blockIdx.x >> 3) * 4 + wid) * 4;
    if (n0 >= N) return;
    int nn[4], st[4], dg[4];
    float ac[4];
    int maxdeg = 0;
#pragma unroll
    for (int k = 0; k < 4; k++) {
        int n = min(n0 + k, N - 1);
        nn[k] = n;
        st[k] = row_start[n];
        dg[k] = cnt[n];
        maxdeg = max(maxdeg, dg[k]);
        ac[k] = 0.f;
    }
    for (int b = 0; b < maxdeg; b += 8) {
        int srcv[4];
        float wv[4];
#pragma unroll
        for (int k = 0; k < 4; k++) {
            int i = b + grp;
            int2 ew = csr[min(st[k] + i, E - 1)];
            bool act = i < dg[k];
            srcv[k] = act ? ew.x : nn[k];
            wv[k] = act ? __int_as_float(ew.y) : 0.f;
        }
#pragma unroll
        for (int k = 0; k < 4; k++) {
            ac[k] += wv[k] * z[(size_t)srcv[k] * 8 + f];
        }
    }
#pragma unroll
    for (int k = 0; k < 4; k++) {
        float a = ac[k];
        a += __shfl_xor(a, 8);
        a += __shfl_xor(a, 16);
        a += __shfl_xor(a, 32);
        float dn = dinv[nn[k]];
        float self = z[(size_t)nn[k] * 8 + f];
        float res = dn * (a + dn * self);
        if (lane < 8 && n0 + k < N) y[(size_t)nn[k] * 8 + lane] = res;
    }
}

// ---------------- dense transform: z = relu(y + bias) @ W, sliced in/out ----------------
// wave processes 16 nodes; W slice held in 64 VGPRs; h broadcast via shfl.

__global__ __launch_bounds__(256) void xform_kernel(
    const float* __restrict__ ys, const float* __restrict__ bias, const float* __restrict__ W,
    float* __restrict__ zs, int N) {
    int lane = threadIdx.x & 63;
    int q = lane >> 4, sl = lane & 15;
    float4 wreg[16];
#pragma unroll
    for (int t = 0; t < 16; t++)
        wreg[t] = *reinterpret_cast<const float4*>(&W[((q << 4) + t) * HID + (sl << 2)]);
    float bl = bias[lane];
    size_t N8 = (size_t)N * 8;
    int n0 = (blockIdx.x * 4 + (threadIdx.x >> 6)) * 16;
    for (int i = 0; i < 16; i++) {
        int n = n0 + i;
        if (n >= N) return;
        float v = ys[(size_t)(lane >> 3) * N8 + (size_t)n * 8 + (lane & 7)];
        float h = fmaxf(v + bl, 0.f);
        float4 zv = make_float4(0.f, 0.f, 0.f, 0.f);
#pragma unroll
        for (int t = 0; t < 16; t++) {
            float hk = __shfl(h, (q << 4) + t);
            zv.x += hk * wreg[t].x; zv.y += hk * wreg[t].y;
            zv.z += hk * wreg[t].z; zv.w += hk * wreg[t].w;
        }
#pragma unroll
        for (int off = 16; off <= 32; off <<= 1) {
            zv.x += __shfl_xor(zv.x, off);
            zv.y += __shfl_xor(zv.y, off);
            zv.z += __shfl_xor(zv.z, off);
            zv.w += __shfl_xor(zv.w, off);
        }
        if (q == 0)
            *reinterpret_cast<float4*>(
                &zs[(size_t)(sl >> 1) * N8 + (size_t)n * 8 + ((sl & 1) << 2)]) = zv;
    }
}

// ---------------- pool: block per graph, no atomics ----------------

__global__ __launch_bounds__(256) void pool_kernel(
    const float* __restrict__ ys, const int* __restrict__ gb,
    float* __restrict__ psum, int* __restrict__ pcnt, int N) {
    int g = blockIdx.x;
    int gs = gb[g], ge = gb[g + 1];
    int wid = threadIdx.x >> 6, lane = threadIdx.x & 63;
    int s = lane >> 3, p = lane & 7;
    float acc = 0.f;
    for (int n = gs + wid; n < ge; n += 4)
        acc += ys[(size_t)s * N * 8 + (size_t)n * 8 + p];
    __shared__ float red[4][HID];
    red[wid][lane] = acc;
    __syncthreads();
    if (wid == 0) {
        float v = red[0][lane] + red[1][lane] + red[2][lane] + red[3][lane];
        psum[(size_t)g * HID + lane] = v;  // dense [G][64]
        if (lane == 0) pcnt[g] = ge - gs;
    }
}

// ---------------- head (adds b3 to pooled mean) ----------------

__global__ void head_kernel(const float* __restrict__ psum, const int* __restrict__ pcnt,
                            const float* __restrict__ b3,
                            const float* __restrict__ dist, const float* __restrict__ sw,
                            const float* __restrict__ Wl, const float* __restrict__ bl,
                            const float* __restrict__ Wl1, const float* __restrict__ bl1,
                            const float* __restrict__ Wl2, const float* __restrict__ bl2,
                            float* __restrict__ out, int G) {
    int g = blockIdx.x * blockDim.x + threadIdx.x;
    if (g >= G) return;
    int c = pcnt[g];
    float invc = 1.f / fmaxf((float)c, 1.f);
    float hasb = (c > 0) ? 1.f : 0.f;
    float a[5];
#pragma unroll
    for (int k = 0; k < 5; k++) a[k] = bl[k];
    for (int j = 0; j < HID; j++) {
        float p = psum[(size_t)g * HID + j] * invc + b3[j] * hasb;
#pragma unroll
        for (int k = 0; k < 5; k++) a[k] += p * Wl[j * 5 + k];
    }
    float g7[7];
#pragma unroll
    for (int k = 0; k < 5; k++) g7[k] = a[k];
    g7[5] = dist[g];
    g7[6] = sw[g];
    float r = bl2[0];
#pragma unroll
    for (int k2 = 0; k2 < 5; k2++) {
        float t = bl1[k2];
#pragma unroll
        for (int j = 0; j < 7; j++) t += g7[j] * Wl1[j * 5 + k2];
        t = fmaxf(t, 0.f);
        r += t * Wl2[k2];
    }
    out[g] = r;
}

// ---------------- launch ----------------

extern "C" void kernel_launch(void* const* d_in, const int* in_sizes, int n_in,
                              void* d_out, int out_size, void* d_ws, size_t ws_size,
                              hipStream_t stream) {
    const float* x    = (const float*)d_in[0];
    const int*   ei   = (const int*)d_in[1];
    const int*   batch= (const int*)d_in[2];
    const float* dist = (const float*)d_in[3];
    const float* sw   = (const float*)d_in[4];
    const float* W1   = (const float*)d_in[5];
    const float* b1   = (const float*)d_in[6];
    const float* W2   = (const float*)d_in[7];
    const float* b2   = (const float*)d_in[8];
    const float* W3   = (const float*)d_in[9];
    const float* b3   = (const float*)d_in[10];
    const float* Wl   = (const float*)d_in[11];
    const float* bl   = (const float*)d_in[12];
    const float* Wl1  = (const float*)d_in[13];
    const float* bl1  = (const float*)d_in[14];
    const float* Wl2  = (const float*)d_in[15];
    const float* bl2  = (const float*)d_in[16];

    int N = in_sizes[0];
    int E = in_sizes[1] / 2;
    int G = in_sizes[3];

    char* ws = (char*)d_ws;
    size_t off = 0;
    auto alloc = [&](size_t bytes) -> char* {
        char* p = ws + off;
        off += (bytes + 255) & ~(size_t)255;
        return p;
    };
    int*   cnt       = (int*)alloc((size_t)N * 4);
    int*   row_start = (int*)alloc((size_t)N * 4);
    int*   cursor    = (int*)alloc((size_t)N * 4);
    float* dinv      = (float*)alloc((size_t)N * 4);
    int*   bsum      = (int*)alloc(SCAN_B * 4);
    int*   bofs      = (int*)alloc(SCAN_B * 4);
    int*   gb        = (int*)alloc(((size_t)G + 1) * 4);
    int2*  csr       = (int2*)alloc((size_t)E * 8);
    float* bufA      = (float*)alloc((size_t)N * HID * 4);  // sliced z
    float* bufB      = (float*)alloc((size_t)N * HID * 4);  // sliced y
    float* psum      = (float*)alloc((size_t)G * HID * 4);
    int*   pcnt      = (int*)alloc((size_t)G * 4);

    hipMemsetAsync(cnt, 0, (size_t)N * 4, stream);

    count_part<<<2048, 256, 0, stream>>>(ei, E, N, cnt);
    dinv_kernel<<<(N + 255) / 256, 256, 0, stream>>>(cnt, dinv, N);
    bounds_kernel<<<(N + 255) / 256, 256, 0, stream>>>(batch, gb, N, G);
    scan_sum<<<SCAN_B, SCAN_T, 0, stream>>>(cnt, N, bsum);
    scan_bsum<<<1, 64, 0, stream>>>(bsum, bofs);
    scan_chunk<<<SCAN_B, SCAN_T, 0, stream>>>(cnt, N, bofs, row_start, cursor);
    fill_part<<<2048, 256, 0, stream>>>(ei, E, N, dinv, cursor, csr);

    int nb = (N + 3) / 4;
    layer1_kernel<<<nb, 256, 0, stream>>>(x, csr, row_start, cnt, dinv, W1, b1, W2, bufA, N);
    int pblocks = NXCD * ((N + 15) / 16);
    psli_kernel<<<pblocks, 256, 0, stream>>>(bufA, csr, row_start, cnt, dinv, bufB, N, E);
    xform_kernel<<<(N + 63) / 64, 256, 0, stream>>>(bufB, b2, W3, bufA, N);
    psli_kernel<<<pblocks, 256, 0, stream>>>(bufA, csr, row_start, cnt, dinv, bufB, N, E);
    pool_kernel<<<G, 256, 0, stream>>>(bufB, gb, psum, pcnt, N);
    head_kernel<<<(G + 255) / 256, 256, 0, stream>>>(psum, pcnt, b3, dist, sw, Wl, bl, Wl1, bl1,
                                                     Wl2, bl2, (float*)d_out, G);
}

// Round 6
// 460.828 us; speedup vs baseline: 1.3738x; 1.3738x over previous
//
#include <hip/hip_runtime.h>
#include <hip/hip_bf16.h>

#define HID 64
#define WPAD 68
#define SCAN_B 128
#define SCAN_T 256
#define NXCD 8

// bf16 helpers: rows are 64 bf16 = 128 B = 16 uint2; lane sl owns uint2[sl] = feats 4sl..4sl+3
static __device__ __forceinline__ float bflo(unsigned u) { return __uint_as_float(u << 16); }
static __device__ __forceinline__ float bfhi(unsigned u) {
    return __uint_as_float(u & 0xFFFF0000u);
}
static __device__ __forceinline__ unsigned packbf(float a, float b) {
    __hip_bfloat16 ha = __float2bfloat16(a), hb = __float2bfloat16(b);
    unsigned short ua = *reinterpret_cast<unsigned short*>(&ha);
    unsigned short ub = *reinterpret_cast<unsigned short*>(&hb);
    return (unsigned)ua | ((unsigned)ub << 16);
}

// ---------------- CSR build (XCD-partitioned by dst range) ----------------

__global__ __launch_bounds__(256) void count_part(const int* __restrict__ ei, int E, int N,
                                                  int* __restrict__ cnt) {
    int xcd = blockIdx.x & (NXCD - 1);
    int sl = blockIdx.x >> 3;
    int nsl = gridDim.x >> 3;
    int nlo = (int)((long long)N * xcd / NXCD);
    int nhi = (int)((long long)N * (xcd + 1) / NXCD);
    int stride = nsl * blockDim.x;
    for (int e = sl * blockDim.x + threadIdx.x; e < E; e += stride) {
        int d = ei[E + e];
        if (d >= nlo && d < nhi) atomicAdd(&cnt[d], 1);
    }
}

__global__ __launch_bounds__(256) void fill_part(const int* __restrict__ ei, int E, int N,
                                                 const float* __restrict__ dinv,
                                                 int* __restrict__ cursor,
                                                 int2* __restrict__ csr) {
    int xcd = blockIdx.x & (NXCD - 1);
    int sl = blockIdx.x >> 3;
    int nsl = gridDim.x >> 3;
    int nlo = (int)((long long)N * xcd / NXCD);
    int nhi = (int)((long long)N * (xcd + 1) / NXCD);
    int stride = nsl * blockDim.x;
    for (int e = sl * blockDim.x + threadIdx.x; e < E; e += stride) {
        int d = ei[E + e];
        if (d >= nlo && d < nhi) {
            int s = ei[e];
            int pos = atomicAdd(&cursor[d], 1);
            csr[pos] = make_int2(s, __float_as_int(dinv[s]));
        }
    }
}

__global__ void dinv_kernel(const int* __restrict__ cnt, float* __restrict__ dinv,
                            const int* __restrict__ batch, int* __restrict__ pcnt, int N) {
    int stride = gridDim.x * blockDim.x;
    for (int n = blockIdx.x * blockDim.x + threadIdx.x; n < N; n += stride) {
        dinv[n] = rsqrtf((float)(cnt[n] + 1));  // deg includes self-loop
        atomicAdd(&pcnt[batch[n]], 1);
    }
}

__global__ void scan_sum(const int* __restrict__ cnt, int N, int* __restrict__ bsum) {
    int b = blockIdx.x;
    int chunk = (N + SCAN_B - 1) / SCAN_B;
    int lo = b * chunk, hi = min(lo + chunk, N);
    int s = 0;
    for (int i = lo + threadIdx.x; i < hi; i += SCAN_T) s += cnt[i];
    for (int off = 32; off; off >>= 1) s += __shfl_xor(s, off);
    __shared__ int red[SCAN_T / 64];
    int wave = threadIdx.x >> 6, lane = threadIdx.x & 63;
    if (lane == 0) red[wave] = s;
    __syncthreads();
    if (threadIdx.x == 0) {
        int t = 0;
        for (int w = 0; w < SCAN_T / 64; w++) t += red[w];
        bsum[b] = t;
    }
}

__global__ void scan_bsum(const int* __restrict__ bsum, int* __restrict__ bofs) {
    if (blockIdx.x == 0 && threadIdx.x == 0) {
        int r = 0;
        for (int b = 0; b < SCAN_B; b++) { bofs[b] = r; r += bsum[b]; }
    }
}

__global__ void scan_chunk(const int* __restrict__ cnt, int N, const int* __restrict__ bofs,
                           int* __restrict__ row_start, int* __restrict__ cursor) {
    int b = blockIdx.x;
    int chunk = (N + SCAN_B - 1) / SCAN_B;
    int lo = b * chunk, hi = min(lo + chunk, N);
    __shared__ int s[SCAN_T];
    __shared__ int carry;
    if (threadIdx.x == 0) carry = bofs[b];
    __syncthreads();
    for (int base = lo; base < hi; base += SCAN_T) {
        int i = base + threadIdx.x;
        int v = (i < hi) ? cnt[i] : 0;
        s[threadIdx.x] = v;
        __syncthreads();
        for (int off = 1; off < SCAN_T; off <<= 1) {
            int t = (threadIdx.x >= off) ? s[threadIdx.x - off] : 0;
            __syncthreads();
            s[threadIdx.x] += t;
            __syncthreads();
        }
        int incl = s[threadIdx.x];
        int c = carry;
        if (i < hi) {
            int ex = c + incl - v;
            row_start[i] = ex;
            cursor[i] = ex;
        }
        __syncthreads();
        if (threadIdx.x == SCAN_T - 1) carry = c + incl;
        __syncthreads();
    }
}

// ---------------- quarter-split fused 64x64 matmul (padded LDS stride) ----------------
__device__ __forceinline__ float4 qmatmul(float4 h4, const float* __restrict__ sW, int q, int sl) {
    float4 z4 = make_float4(0.f, 0.f, 0.f, 0.f);
#pragma unroll
    for (int t = 0; t < 16; t++) {
        int k = (q << 4) + t;
        int srclane = 20 * q + (t >> 2);
        float comp = ((t & 3) == 0) ? h4.x : ((t & 3) == 1) ? h4.y : ((t & 3) == 2) ? h4.z : h4.w;
        float hk = __shfl(comp, srclane);
        const float4 w4 = *reinterpret_cast<const float4*>(&sW[k * WPAD + sl * 4]);
        z4.x += hk * w4.x; z4.y += hk * w4.y; z4.z += hk * w4.z; z4.w += hk * w4.w;
    }
#pragma unroll
    for (int off = 16; off <= 32; off <<= 1) {
        z4.x += __shfl_xor(z4.x, off);
        z4.y += __shfl_xor(z4.y, off);
        z4.z += __shfl_xor(z4.z, off);
        z4.w += __shfl_xor(z4.w, off);
    }
    return z4;
}

__device__ __forceinline__ void stageW(const float* __restrict__ W, float* __restrict__ sW) {
    for (int i = threadIdx.x; i < HID * HID; i += 256) {
        int r = i >> 6, c = i & 63;
        sW[r * WPAD + c] = W[i];
    }
    __syncthreads();
}

// ---------------- Layer 1: scalar propagate + fused (relu(p*W1+b1)) @ W2 -> bf16 ----------

__global__ __launch_bounds__(256) void layer1_kernel(
    const float* __restrict__ x, const int2* __restrict__ csr,
    const int* __restrict__ row_start, const int* __restrict__ cnt, const float* __restrict__ dinv,
    const float* __restrict__ W1, const float* __restrict__ b1, const float* __restrict__ W2,
    uint2* __restrict__ zb, int N) {
    __shared__ float sW2[HID * WPAD];
    stageW(W2, sW2);
    int lane = threadIdx.x & 63;
    int q = lane >> 4, sl = lane & 15;
    int n = blockIdx.x * 4 + (threadIdx.x >> 6);
    if (n >= N) return;
    int start = row_start[n], deg = cnt[n];
    float acc = 0.f;
    for (int i = start + lane; i < start + deg; i += 64) {
        int2 ew = csr[i];
        acc += __int_as_float(ew.y) * x[ew.x];
    }
#pragma unroll
    for (int off = 32; off; off >>= 1) acc += __shfl_xor(acc, off);
    float dn = dinv[n];
    float p = dn * (acc + dn * x[n]);  // wave-uniform
    float h = fmaxf(p * W1[lane] + b1[lane], 0.f);  // one feature per lane
    float4 h4;
    h4.x = __shfl(h, (sl << 2) + 0);
    h4.y = __shfl(h, (sl << 2) + 1);
    h4.z = __shfl(h, (sl << 2) + 2);
    h4.w = __shfl(h, (sl << 2) + 3);
    float4 z4 = qmatmul(h4, sW2, q, sl);
    if (q == 0)
        zb[(size_t)n * 16 + sl] = make_uint2(packbf(z4.x, z4.y), packbf(z4.z, z4.w));
}

// ---------------- 64-wide propagate over bf16 rows (layers 2,3) ----------------
// Gather: 4 edges per wave-instruction, 1 cache line per row (128 B bf16).
// FUSE: out = relu(P(zin)+bias) @ W -> bf16   (layer 2)
// POOL: segmented LDS reduction + one fp32 atomic run per distinct graph (layer 3 + pool)

template <bool FUSE, bool POOL>
__global__ __launch_bounds__(256) void p64_kernel(
    const uint2* __restrict__ zb, const int2* __restrict__ csr,
    const int* __restrict__ row_start, const int* __restrict__ cnt, const float* __restrict__ dinv,
    const float* __restrict__ bias, const float* __restrict__ W,
    uint2* __restrict__ outb, float* __restrict__ outp, const int* __restrict__ batch, int N) {
    __shared__ float sW[FUSE ? HID * WPAD : 1];
    __shared__ float pbuf[POOL ? 4 : 1][POOL ? HID : 1];
    __shared__ int pg[4];
    if (FUSE) stageW(W, sW);
    int lane = threadIdx.x & 63;
    int wid = threadIdx.x >> 6;
    int q = lane >> 4, sl = lane & 15;
    int n = blockIdx.x * 4 + wid;
    bool valid = n < N;
    if (!POOL && !valid) return;

    float4 acc = make_float4(0.f, 0.f, 0.f, 0.f);
    if (valid) {
        int start = row_start[n], deg = cnt[n];
        float dn = dinv[n];
        uint2 su = zb[(size_t)n * 16 + sl];
        for (int base = 0; base < deg; base += 64) {
            int m = deg - base; if (m > 64) m = 64;
            int2 ew = (lane < m) ? csr[start + base + lane] : make_int2(0, 0);
            int mt = (m + 3) >> 2;
            for (int tb = 0; tb < mt; tb += 4) {
#pragma unroll
                for (int k = 0; k < 4; k++) {
                    int t = tb + k;
                    bool act = t < mt;
                    int eidx = ((t << 2) + q) & 63;
                    int ss = __shfl(ew.x, eidx);
                    float ww = __int_as_float(__shfl(ew.y, eidx));
                    ss = act ? ss : 0;
                    ww = act ? ww : 0.f;
                    const uint2 row = zb[(size_t)ss * 16 + sl];
                    acc.x += ww * bflo(row.x); acc.y += ww * bfhi(row.x);
                    acc.z += ww * bflo(row.y); acc.w += ww * bfhi(row.y);
                }
            }
        }
#pragma unroll
        for (int off = 16; off <= 32; off <<= 1) {
            acc.x += __shfl_xor(acc.x, off);
            acc.y += __shfl_xor(acc.y, off);
            acc.z += __shfl_xor(acc.z, off);
            acc.w += __shfl_xor(acc.w, off);
        }
        const float4 b4 = *reinterpret_cast<const float4*>(&bias[sl << 2]);
        acc.x = dn * (acc.x + dn * bflo(su.x)) + b4.x;
        acc.y = dn * (acc.y + dn * bfhi(su.x)) + b4.y;
        acc.z = dn * (acc.z + dn * bflo(su.y)) + b4.z;
        acc.w = dn * (acc.w + dn * bfhi(su.y)) + b4.w;
    }

    if (FUSE) {
        float4 h4;
        h4.x = fmaxf(acc.x, 0.f); h4.y = fmaxf(acc.y, 0.f);
        h4.z = fmaxf(acc.z, 0.f); h4.w = fmaxf(acc.w, 0.f);
        float4 z4 = qmatmul(h4, sW, q, sl);
        if (q == 0)
            outb[(size_t)n * 16 + sl] = make_uint2(packbf(z4.x, z4.y), packbf(z4.z, z4.w));
    } else if (POOL) {
        if (q == 0) {
            *reinterpret_cast<float4*>(&pbuf[wid][sl << 2]) = acc;
            if (sl == 0) pg[wid] = valid ? batch[n] : -1;
        }
        __syncthreads();
        if (wid == 0) {
            int j = lane;
            float v = 0.f;
            int gp = -1;
#pragma unroll
            for (int w = 0; w < 4; w++) {
                int gw = pg[w];  // wave-uniform
                if (gw < 0) continue;
                if (gw == gp) {
                    v += pbuf[w][j];
                } else {
                    if (gp >= 0) atomicAdd(&outp[(size_t)gp * HID + j], v);
                    v = pbuf[w][j];
                    gp = gw;
                }
            }
            if (gp >= 0) atomicAdd(&outp[(size_t)gp * HID + j], v);
        }
    }
}

// ---------------- head ----------------

__global__ void head_kernel(const float* __restrict__ psum, const int* __restrict__ pcnt,
                            const float* __restrict__ dist, const float* __restrict__ sw,
                            const float* __restrict__ Wl, const float* __restrict__ bl,
                            const float* __restrict__ Wl1, const float* __restrict__ bl1,
                            const float* __restrict__ Wl2, const float* __restrict__ bl2,
                            float* __restrict__ out, int G) {
    int g = blockIdx.x * blockDim.x + threadIdx.x;
    if (g >= G) return;
    float invc = 1.f / fmaxf((float)pcnt[g], 1.f);
    float a[5];
#pragma unroll
    for (int k = 0; k < 5; k++) a[k] = bl[k];
    for (int j = 0; j < HID; j++) {
        float p = psum[(size_t)g * HID + j] * invc;
#pragma unroll
        for (int k = 0; k < 5; k++) a[k] += p * Wl[j * 5 + k];
    }
    float g7[7];
#pragma unroll
    for (int k = 0; k < 5; k++) g7[k] = a[k];
    g7[5] = dist[g];
    g7[6] = sw[g];
    float r = bl2[0];
#pragma unroll
    for (int k2 = 0; k2 < 5; k2++) {
        float t = bl1[k2];
#pragma unroll
        for (int j = 0; j < 7; j++) t += g7[j] * Wl1[j * 5 + k2];
        t = fmaxf(t, 0.f);
        r += t * Wl2[k2];
    }
    out[g] = r;
}

// ---------------- launch ----------------

extern "C" void kernel_launch(void* const* d_in, const int* in_sizes, int n_in,
                              void* d_out, int out_size, void* d_ws, size_t ws_size,
                              hipStream_t stream) {
    const float* x    = (const float*)d_in[0];
    const int*   ei   = (const int*)d_in[1];
    const int*   batch= (const int*)d_in[2];
    const float* dist = (const float*)d_in[3];
    const float* sw   = (const float*)d_in[4];
    const float* W1   = (const float*)d_in[5];
    const float* b1   = (const float*)d_in[6];
    const float* W2   = (const float*)d_in[7];
    const float* b2   = (const float*)d_in[8];
    const float* W3   = (const float*)d_in[9];
    const float* b3   = (const float*)d_in[10];
    const float* Wl   = (const float*)d_in[11];
    const float* bl   = (const float*)d_in[12];
    const float* Wl1  = (const float*)d_in[13];
    const float* bl1  = (const float*)d_in[14];
    const float* Wl2  = (const float*)d_in[15];
    const float* bl2  = (const float*)d_in[16];

    int N = in_sizes[0];
    int E = in_sizes[1] / 2;
    int G = in_sizes[3];

    char* ws = (char*)d_ws;
    size_t off = 0;
    auto alloc = [&](size_t bytes) -> char* {
        char* p = ws + off;
        off += (bytes + 255) & ~(size_t)255;
        return p;
    };
    int*   cnt       = (int*)alloc((size_t)N * 4);
    int*   row_start = (int*)alloc((size_t)N * 4);
    int*   cursor    = (int*)alloc((size_t)N * 4);
    float* dinv      = (float*)alloc((size_t)N * 4);
    int*   bsum      = (int*)alloc(SCAN_B * 4);
    int*   bofs      = (int*)alloc(SCAN_B * 4);
    int2*  csr       = (int2*)alloc((size_t)E * 8);
    uint2* bufA      = (uint2*)alloc((size_t)N * HID * 2);  // bf16 rows (128 B)
    uint2* bufB      = (uint2*)alloc((size_t)N * HID * 2);
    float* psum      = (float*)alloc((size_t)G * HID * 4);
    int*   pcnt      = (int*)alloc((size_t)G * 4);

    hipMemsetAsync(cnt, 0, (size_t)N * 4, stream);
    hipMemsetAsync(psum, 0, (size_t)G * HID * 4, stream);
    hipMemsetAsync(pcnt, 0, (size_t)G * 4, stream);

    count_part<<<2048, 256, 0, stream>>>(ei, E, N, cnt);
    dinv_kernel<<<(N + 255) / 256, 256, 0, stream>>>(cnt, dinv, batch, pcnt, N);
    scan_sum<<<SCAN_B, SCAN_T, 0, stream>>>(cnt, N, bsum);
    scan_bsum<<<1, 64, 0, stream>>>(bsum, bofs);
    scan_chunk<<<SCAN_B, SCAN_T, 0, stream>>>(cnt, N, bofs, row_start, cursor);
    fill_part<<<2048, 256, 0, stream>>>(ei, E, N, dinv, cursor, csr);

    int nb = (N + 3) / 4;
    layer1_kernel<<<nb, 256, 0, stream>>>(x, csr, row_start, cnt, dinv, W1, b1, W2, bufA, N);
    p64_kernel<true, false><<<nb, 256, 0, stream>>>(bufA, csr, row_start, cnt, dinv, b2, W3,
                                                    bufB, nullptr, nullptr, N);
    p64_kernel<false, true><<<nb, 256, 0, stream>>>(bufB, csr, row_start, cnt, dinv, b3, nullptr,
                                                    nullptr, psum, batch, N);
    head_kernel<<<(G + 255) / 256, 256, 0, stream>>>(psum, pcnt, dist, sw, Wl, bl, Wl1, bl1, Wl2,
                                                     bl2, (float*)d_out, G);
}